// Round 5
// baseline (166.111 us; speedup 1.0000x reference)
//
#include <hip/hip_runtime.h>
#include <hip/hip_bf16.h>

#define NN 8192
#define IN_F 256
#define OF 128

typedef float  f32x4   __attribute__((ext_vector_type(4)));
typedef short  short4v __attribute__((ext_vector_type(4)));
typedef short  short8v __attribute__((ext_vector_type(8)));
typedef int    int4v   __attribute__((ext_vector_type(4)));

__device__ __forceinline__ unsigned short bf16_bits(float x) {
    __bf16 b = (__bf16)x;
    return __builtin_bit_cast(unsigned short, b);
}

__device__ __forceinline__ f32x4 mfma16(short4v a, short4v b, f32x4 c) {
#if __has_builtin(__builtin_amdgcn_mfma_f32_16x16x16bf16_1k)
    return __builtin_amdgcn_mfma_f32_16x16x16bf16_1k(a, b, c, 0, 0, 0);
#else
    asm("v_mfma_f32_16x16x16_bf16 %0, %1, %2, %0" : "+v"(c) : "v"(a), "v"(b));
    return c;
#endif
}

// ---------------------------------------------------------------------------
// Kernel A: h = X @ W (f32, LDS-staged W).  Emits HtB in MFMA-B-fragment
// order (verified R3):  for h[j][f]:
//   tile=j>>4, g=(j>>2)&3, e=j&3, np=f>>5, o=(f>>4)&1, c=f&15
//   idx = ((tile*4+np)*64 + g*16 + c)*8 + o*4 + e
// Also f_src = h.a[:OF], f_dst = h.a[OF:].
// ---------------------------------------------------------------------------
__global__ __launch_bounds__(256) void gat_prep(
    const float* __restrict__ X, const float* __restrict__ W,
    const float* __restrict__ a, unsigned short* __restrict__ HtB,
    float* __restrict__ f_src, float* __restrict__ f_dst)
{
    __shared__ float Wlds[IN_F * OF];   // 128 KiB
    __shared__ float red_s[32][8];
    __shared__ float red_d[32][8];

    const int t = threadIdx.x;
    {
        const f32x4* Wv = (const f32x4*)W;
        f32x4*       Wl = (f32x4*)Wlds;
        #pragma unroll
        for (int c = 0; c < 32; ++c) Wl[c * 256 + t] = Wv[c * 256 + t];
    }
    __syncthreads();

    const int row = t & 31;
    const int sub = t >> 5;
    const int i   = blockIdx.x * 32 + row;

    f32x4 acc[4] = {};
    const float* xrow = X + (size_t)i * IN_F;

    #pragma unroll 4
    for (int kk = 0; kk < IN_F; kk += 4) {
        f32x4 xv = *(const f32x4*)(xrow + kk);
        #pragma unroll
        for (int e = 0; e < 4; ++e) {
            const f32x4* wr = (const f32x4*)(Wlds + (kk + e) * OF + sub * 16);
            float xs = xv[e];
            #pragma unroll
            for (int c4 = 0; c4 < 4; ++c4) acc[c4] += xs * wr[c4];
        }
    }

    const int tile = i >> 4;
    const int gq   = (i >> 2) & 3;
    const int eq   = i & 3;
    const int np   = sub >> 1;
    const int oo   = sub & 1;

    float ps = 0.f, pd = 0.f;
    #pragma unroll
    for (int c4 = 0; c4 < 4; ++c4) {
        #pragma unroll
        for (int e = 0; e < 4; ++e) {
            float v = acc[c4][e];
            int   c = c4 * 4 + e;
            ps += v * a[sub * 16 + c];
            pd += v * a[OF + sub * 16 + c];
            HtB[(size_t)(((tile * 4 + np) * 64) + gq * 16 + c) * 8 + oo * 4 + eq]
                = bf16_bits(v);
        }
    }
    red_s[row][sub] = ps;
    red_d[row][sub] = pd;
    __syncthreads();
    if (t < 32) {
        float s = 0.f;
        #pragma unroll
        for (int s8 = 0; s8 < 8; ++s8) s += red_s[t][s8];
        f_src[blockIdx.x * 32 + t] = s;
    } else if (t < 64) {
        const int r2 = t - 32;
        float s = 0.f;
        #pragma unroll
        for (int s8 = 0; s8 < 8; ++s8) s += red_d[r2][s8];
        f_dst[blockIdx.x * 32 + r2] = s;
    }
}

// ---------------------------------------------------------------------------
// Kernel B v5: flash-GAT at FULL occupancy.
// 512 blocks x 1024 threads (16 waves) = 2 blocks/CU, 32 waves/CU, 8/SIMD.
// Wave = (jw, fw): jw in [0,8) strides j-tiles by 8; fw in [0,2) halves the
// feature dim (64 features each) -> acc is only f32x4[4] so the body fits the
// 64-VGPR budget that 8 waves/SIMD requires (__launch_bounds__(1024, 8)).
// adj is read by both fw twins of a jw -> same CU -> L1 absorbs the 2x.
// MFMA 16x16x16 bf16 fragments as verified in R3.
// ---------------------------------------------------------------------------
__global__ __launch_bounds__(1024, 8) void gat_flash(
    const int* __restrict__ adj, const unsigned short* __restrict__ HtB,
    const float* __restrict__ f_src, const float* __restrict__ f_dst,
    float* __restrict__ out)
{
    __shared__ float red[8][16][OF];   // 64 KiB
    __shared__ float rden[8][16];

    const int tid  = threadIdx.x;
    const int wave = tid >> 6;
    const int lane = tid & 63;
    const int jw   = wave & 7;
    const int fw   = wave >> 3;
    const int r    = lane & 15;
    const int g    = lane >> 4;
    const int rowbase = blockIdx.x * 16;

    const float fsrc_r = f_src[rowbase + r];
    const int*   aptr = adj + (size_t)(rowbase + r) * NN + g * 4;
    const float* fptr = f_dst + g * 4;
    const short8v* htv = (const short8v*)HtB;

    f32x4 acc[4] = {};
    float psum = 0.f;

    // depth-2 rotation on adj (the HBM stream)
    int4v pa0 = *(const int4v*)(aptr + (jw + 0) * 16);
    int4v pa1 = *(const int4v*)(aptr + (jw + 8) * 16);

    for (int it = 0; it < 64; ++it) {
        const int tile = jw + it * 8;

        // two 1KB contiguous HtB fragment loads (this wave's 64 features)
        short8v bp0 = htv[(size_t)(tile * 4 + fw * 2 + 0) * 64 + lane];
        short8v bp1 = htv[(size_t)(tile * 4 + fw * 2 + 1) * 64 + lane];

        // rotate adj pipeline; prefetch it+2
        const int4v a_cur = pa0;
        pa0 = pa1;
        const int pt = (it + 2 < 64) ? tile + 16 : tile;
        pa1 = *(const int4v*)(aptr + pt * 16);

        const f32x4 f_cur = *(const f32x4*)(fptr + tile * 16);

        float p[4];
        #pragma unroll
        for (int e = 0; e < 4; ++e) {
            float s = fsrc_r + f_cur[e];
            s = s > 0.f ? s : 0.2f * s;              // leaky_relu
            p[e] = (a_cur[e] != 0) ? __expf(s) : 0.f;
        }
        psum += (p[0] + p[1]) + (p[2] + p[3]);
        short4v af = { (short)bf16_bits(p[0]), (short)bf16_bits(p[1]),
                       (short)bf16_bits(p[2]), (short)bf16_bits(p[3]) };

        acc[0] = mfma16(af, __builtin_shufflevector(bp0, bp0, 0, 1, 2, 3), acc[0]);
        acc[1] = mfma16(af, __builtin_shufflevector(bp0, bp0, 4, 5, 6, 7), acc[1]);
        acc[2] = mfma16(af, __builtin_shufflevector(bp1, bp1, 0, 1, 2, 3), acc[2]);
        acc[3] = mfma16(af, __builtin_shufflevector(bp1, bp1, 4, 5, 6, 7), acc[3]);
    }

    // each (jw,fw) wave owns a disjoint slab slice -> single write round
    #pragma unroll
    for (int lp = 0; lp < 2; ++lp)
        #pragma unroll
        for (int o = 0; o < 2; ++o)
            #pragma unroll
            for (int q = 0; q < 4; ++q)
                red[jw][g * 4 + q][(fw * 4 + lp * 2 + o) * 16 + r] = acc[lp * 2 + o][q];

    if (fw == 0) {
        // denom: reduce psum over the 4 k-groups (fw=0 waves only; fw=1 is a dup)
        psum += __shfl_xor(psum, 16, 64);
        psum += __shfl_xor(psum, 32, 64);
        if (lane < 16) rden[jw][lane] = psum;
    }
    __syncthreads();

    // epilogue: 512 threads x 1 f32x4 = 16x128 tile
    if (tid < 512) {
        const int orow = tid >> 5;
        const int cg   = tid & 31;
        f32x4 v = {};
        float den = 0.f;
        #pragma unroll
        for (int w = 0; w < 8; ++w) {
            v   += *(const f32x4*)&red[w][orow][cg * 4];
            den += rden[w][orow];
        }
        const float inv = 1.0f / den;
        f32x4 o = v * inv;
        #pragma unroll
        for (int e = 0; e < 4; ++e) o[e] = fmaxf(o[e], 0.f);
        *(f32x4*)(out + (size_t)(rowbase + orow) * OF + cg * 4) = o;
    }
}

extern "C" void kernel_launch(void* const* d_in, const int* in_sizes, int n_in,
                              void* d_out, int out_size, void* d_ws, size_t ws_size,
                              hipStream_t stream) {
    const float* X   = (const float*)d_in[0];
    const int*   adj = (const int*)d_in[1];
    const float* W   = (const float*)d_in[2];
    const float* a   = (const float*)d_in[3];
    float* out = (float*)d_out;

    unsigned short* HtB = (unsigned short*)d_ws;                    // 2 MiB
    float* f_src = (float*)((char*)d_ws + (size_t)OF * NN * sizeof(unsigned short));
    float* f_dst = f_src + NN;

    gat_prep<<<NN / 32, 256, 0, stream>>>(X, W, a, HtB, f_src, f_dst);
    gat_flash<<<NN / 16, 1024, 0, stream>>>(adj, HtB, f_src, f_dst, out);
}

// Round 6
// 153.176 us; speedup vs baseline: 1.0844x; 1.0844x over previous
//
#include <hip/hip_runtime.h>
#include <hip/hip_bf16.h>

#define NN 8192
#define IN_F 256
#define OF 128

typedef float  f32x4   __attribute__((ext_vector_type(4)));
typedef short  short4v __attribute__((ext_vector_type(4)));
typedef short  short8v __attribute__((ext_vector_type(8)));
typedef int    int4v   __attribute__((ext_vector_type(4)));

__device__ __forceinline__ unsigned short bf16_bits(float x) {
    __bf16 b = (__bf16)x;
    return __builtin_bit_cast(unsigned short, b);
}

__device__ __forceinline__ f32x4 mfma16(short4v a, short4v b, f32x4 c) {
#if __has_builtin(__builtin_amdgcn_mfma_f32_16x16x16bf16_1k)
    return __builtin_amdgcn_mfma_f32_16x16x16bf16_1k(a, b, c, 0, 0, 0);
#else
    asm("v_mfma_f32_16x16x16_bf16 %0, %1, %2, %0" : "+v"(c) : "v"(a), "v"(b));
    return c;
#endif
}

// ---------------------------------------------------------------------------
// Kernel A: h = X @ W (f32, LDS-staged W).  Emits HtB in MFMA-B-fragment
// order (verified R3):  for h[j][f]:
//   tile=j>>4, g=(j>>2)&3, e=j&3, np=f>>5, o=(f>>4)&1, c=f&15
//   idx = ((tile*4+np)*64 + g*16 + c)*8 + o*4 + e
// Also f_src = h.a[:OF], f_dst = h.a[OF:].
// ---------------------------------------------------------------------------
__global__ __launch_bounds__(256) void gat_prep(
    const float* __restrict__ X, const float* __restrict__ W,
    const float* __restrict__ a, unsigned short* __restrict__ HtB,
    float* __restrict__ f_src, float* __restrict__ f_dst)
{
    __shared__ float Wlds[IN_F * OF];   // 128 KiB
    __shared__ float red_s[32][8];
    __shared__ float red_d[32][8];

    const int t = threadIdx.x;
    {
        const f32x4* Wv = (const f32x4*)W;
        f32x4*       Wl = (f32x4*)Wlds;
        #pragma unroll
        for (int c = 0; c < 32; ++c) Wl[c * 256 + t] = Wv[c * 256 + t];
    }
    __syncthreads();

    const int row = t & 31;
    const int sub = t >> 5;
    const int i   = blockIdx.x * 32 + row;

    f32x4 acc[4] = {};
    const float* xrow = X + (size_t)i * IN_F;

    #pragma unroll 4
    for (int kk = 0; kk < IN_F; kk += 4) {
        f32x4 xv = *(const f32x4*)(xrow + kk);
        #pragma unroll
        for (int e = 0; e < 4; ++e) {
            const f32x4* wr = (const f32x4*)(Wlds + (kk + e) * OF + sub * 16);
            float xs = xv[e];
            #pragma unroll
            for (int c4 = 0; c4 < 4; ++c4) acc[c4] += xs * wr[c4];
        }
    }

    const int tile = i >> 4;
    const int gq   = (i >> 2) & 3;
    const int eq   = i & 3;
    const int np   = sub >> 1;
    const int oo   = sub & 1;

    float ps = 0.f, pd = 0.f;
    #pragma unroll
    for (int c4 = 0; c4 < 4; ++c4) {
        #pragma unroll
        for (int e = 0; e < 4; ++e) {
            float v = acc[c4][e];
            int   c = c4 * 4 + e;
            ps += v * a[sub * 16 + c];
            pd += v * a[OF + sub * 16 + c];
            HtB[(size_t)(((tile * 4 + np) * 64) + gq * 16 + c) * 8 + oo * 4 + eq]
                = bf16_bits(v);
        }
    }
    red_s[row][sub] = ps;
    red_d[row][sub] = pd;
    __syncthreads();
    if (t < 32) {
        float s = 0.f;
        #pragma unroll
        for (int s8 = 0; s8 < 8; ++s8) s += red_s[t][s8];
        f_src[blockIdx.x * 32 + t] = s;
    } else if (t < 64) {
        const int r2 = t - 32;
        float s = 0.f;
        #pragma unroll
        for (int s8 = 0; s8 < 8; ++s8) s += red_d[r2][s8];
        f_dst[blockIdx.x * 32 + r2] = s;
    }
}

// ---------------------------------------------------------------------------
// Kernel B v6: flash-GAT with HtB amortization.
// 256 blocks x 1024 threads (16 waves), 32 ROWS per block -> total HtB
// traffic from L2 halves (1 GiB -> 512 MiB); adj still read exactly once.
// Wave = (jw, fw): jw strides j-tiles by 8, fw halves features.
// Each wave computes BOTH 16-row groups (m=0,1): two A-fragments share the
// B-fragments and f_dst values. Fragments/layout verified in R3.
// ---------------------------------------------------------------------------
__global__ __launch_bounds__(1024, 4) void gat_flash(
    const int* __restrict__ adj, const unsigned short* __restrict__ HtB,
    const float* __restrict__ f_src, const float* __restrict__ f_dst,
    float* __restrict__ out)
{
    __shared__ float red[4][32][OF];   // 64 KiB
    __shared__ float rden[8][32];

    const int tid  = threadIdx.x;
    const int wave = tid >> 6;
    const int lane = tid & 63;
    const int jw   = wave & 7;
    const int fw   = wave >> 3;
    const int r    = lane & 15;
    const int g    = lane >> 4;
    const int rowbase = blockIdx.x * 32;

    const float fsrc0 = f_src[rowbase + r];
    const float fsrc1 = f_src[rowbase + 16 + r];
    const int* aptr0 = adj + (size_t)(rowbase + r) * NN + g * 4;
    const int* aptr1 = adj + (size_t)(rowbase + 16 + r) * NN + g * 4;
    const float* fptr = f_dst + g * 4;
    const short8v* htv = (const short8v*)HtB;

    f32x4 acc[2][4] = {};
    float psum0 = 0.f, psum1 = 0.f;

    // depth-2 rotation on the adj HBM streams (both row groups)
    int4v a00 = *(const int4v*)(aptr0 + (jw + 0) * 16);
    int4v a01 = *(const int4v*)(aptr0 + (jw + 8) * 16);
    int4v a10 = *(const int4v*)(aptr1 + (jw + 0) * 16);
    int4v a11 = *(const int4v*)(aptr1 + (jw + 8) * 16);

    for (int it = 0; it < 64; ++it) {
        const int tile = jw + it * 8;

        // two 1KB contiguous HtB fragment loads (this wave's 64 features)
        short8v bp0 = htv[(size_t)(tile * 4 + fw * 2 + 0) * 64 + lane];
        short8v bp1 = htv[(size_t)(tile * 4 + fw * 2 + 1) * 64 + lane];

        // rotate adj pipelines; prefetch it+2
        const int4v ac0 = a00, ac1 = a10;
        a00 = a01; a10 = a11;
        const int pt = (it + 2 < 64) ? tile + 16 : tile;
        a01 = *(const int4v*)(aptr0 + pt * 16);
        a11 = *(const int4v*)(aptr1 + pt * 16);

        const f32x4 f_cur = *(const f32x4*)(fptr + tile * 16);

        float p0[4], p1[4];
        #pragma unroll
        for (int e = 0; e < 4; ++e) {
            float s0 = fsrc0 + f_cur[e];
            s0 = s0 > 0.f ? s0 : 0.2f * s0;          // leaky_relu
            p0[e] = (ac0[e] != 0) ? __expf(s0) : 0.f;
            float s1 = fsrc1 + f_cur[e];
            s1 = s1 > 0.f ? s1 : 0.2f * s1;
            p1[e] = (ac1[e] != 0) ? __expf(s1) : 0.f;
        }
        psum0 += (p0[0] + p0[1]) + (p0[2] + p0[3]);
        psum1 += (p1[0] + p1[1]) + (p1[2] + p1[3]);
        short4v af0 = { (short)bf16_bits(p0[0]), (short)bf16_bits(p0[1]),
                        (short)bf16_bits(p0[2]), (short)bf16_bits(p0[3]) };
        short4v af1 = { (short)bf16_bits(p1[0]), (short)bf16_bits(p1[1]),
                        (short)bf16_bits(p1[2]), (short)bf16_bits(p1[3]) };

        const short4v b0l = __builtin_shufflevector(bp0, bp0, 0, 1, 2, 3);
        const short4v b0h = __builtin_shufflevector(bp0, bp0, 4, 5, 6, 7);
        const short4v b1l = __builtin_shufflevector(bp1, bp1, 0, 1, 2, 3);
        const short4v b1h = __builtin_shufflevector(bp1, bp1, 4, 5, 6, 7);

        acc[0][0] = mfma16(af0, b0l, acc[0][0]);
        acc[0][1] = mfma16(af0, b0h, acc[0][1]);
        acc[0][2] = mfma16(af0, b1l, acc[0][2]);
        acc[0][3] = mfma16(af0, b1h, acc[0][3]);
        acc[1][0] = mfma16(af1, b0l, acc[1][0]);
        acc[1][1] = mfma16(af1, b0h, acc[1][1]);
        acc[1][2] = mfma16(af1, b1l, acc[1][2]);
        acc[1][3] = mfma16(af1, b1h, acc[1][3]);
    }

    // denom: reduce over the 4 k-groups; fw==0 waves own the writes
    psum0 += __shfl_xor(psum0, 16, 64);
    psum0 += __shfl_xor(psum0, 32, 64);
    psum1 += __shfl_xor(psum1, 16, 64);
    psum1 += __shfl_xor(psum1, 32, 64);
    if (fw == 0 && lane < 16) {
        rden[jw][r]      = psum0;
        rden[jw][16 + r] = psum1;
    }

    // tree reduction across jw: 4-7 write, 0-3 add (disjoint in fw)
    if (jw >= 4) {
        #pragma unroll
        for (int m = 0; m < 2; ++m)
            #pragma unroll
            for (int nf = 0; nf < 4; ++nf)
                #pragma unroll
                for (int q = 0; q < 4; ++q)
                    red[jw - 4][m * 16 + g * 4 + q][fw * 64 + nf * 16 + r]
                        = acc[m][nf][q];
    }
    __syncthreads();
    if (jw < 4) {
        #pragma unroll
        for (int m = 0; m < 2; ++m)
            #pragma unroll
            for (int nf = 0; nf < 4; ++nf)
                #pragma unroll
                for (int q = 0; q < 4; ++q)
                    red[jw][m * 16 + g * 4 + q][fw * 64 + nf * 16 + r]
                        += acc[m][nf][q];
    }
    __syncthreads();

    // epilogue: 1024 threads x 1 f32x4 = 32x128 tile
    const int orow = tid >> 5;     // 0..31
    const int cg   = tid & 31;     // 4-col group
    f32x4 v = {};
    #pragma unroll
    for (int w = 0; w < 4; ++w)
        v += *(const f32x4*)&red[w][orow][cg * 4];
    float den = 0.f;
    #pragma unroll
    for (int w = 0; w < 8; ++w) den += rden[w][orow];
    const float inv = 1.0f / den;
    f32x4 o = v * inv;
    #pragma unroll
    for (int e = 0; e < 4; ++e) o[e] = fmaxf(o[e], 0.f);
    *(f32x4*)(out + (size_t)(rowbase + orow) * OF + cg * 4) = o;
}

extern "C" void kernel_launch(void* const* d_in, const int* in_sizes, int n_in,
                              void* d_out, int out_size, void* d_ws, size_t ws_size,
                              hipStream_t stream) {
    const float* X   = (const float*)d_in[0];
    const int*   adj = (const int*)d_in[1];
    const float* W   = (const float*)d_in[2];
    const float* a   = (const float*)d_in[3];
    float* out = (float*)d_out;

    unsigned short* HtB = (unsigned short*)d_ws;                    // 2 MiB
    float* f_src = (float*)((char*)d_ws + (size_t)OF * NN * sizeof(unsigned short));
    float* f_dst = f_src + NN;

    gat_prep<<<NN / 32, 256, 0, stream>>>(X, W, a, HtB, f_src, f_dst);
    gat_flash<<<NN / 32, 1024, 0, stream>>>(adj, HtB, f_src, f_dst, out);
}